// Round 4
// baseline (854.222 us; speedup 1.0000x reference)
//
#include <hip/hip_runtime.h>
#include <hip/hip_bf16.h>
#include <math.h>

#define NQ 8192
#define NK 524288
#define NB 128
#define NF 64
#define ND 128
#define EPSF 1e-8f

using bf16x8 = __attribute__((ext_vector_type(8))) short;
using f32x4  = __attribute__((ext_vector_type(4))) float;

__device__ __forceinline__ unsigned short f2bf(float x) {
    union { float f; unsigned int u; } v; v.f = x;
    unsigned int u = v.u;
    return (unsigned short)((u + 0x7FFFu + ((u >> 16) & 1u)) >> 16);
}

// Bfrag layout: [kc(6)][nt(8)][lane(64)][j(8)] bf16, B[k][n] with
// n = nt*16 + (lane&15), k = kc*32 + (lane>>4)*8 + j ; value = content(k) of col n
__device__ __forceinline__ int frag_index(int k, int b) {
    int kc = k >> 5, kl = k & 31, quad = kl >> 3, j = kl & 7;
    int nt = b >> 4, ln = (quad << 4) | (b & 15);
    return ((kc * 8 + nt) * 64 + ln) * 8 + j;
}

// ---------------- prep: rotated probes, softplus weights, frag scatter ------
// Mag k-slots are PERMUTED so k_gemm lanes can build mag frags from their own
// dot-load registers: slot (kc=4+h, quad, j) holds mag index
// f = (2h + (j>>2))*16 + quad*4 + (j&3). Inverse used here:
// k(f) = (4 + (f>>5))*32 + ((f>>2)&3)*8 + ((f>>4)&1)*4 + (f&3).
__global__ void prep_kernel(const float* __restrict__ angles,
                            const float* __restrict__ probes,
                            const float* __restrict__ kmw,
                            const float* __restrict__ qwr,
                            const float* __restrict__ qmw,
                            unsigned short* __restrict__ Bfrag,
                            float4* __restrict__ Ppack) {
    int t = threadIdx.x;          // 256 threads: 2 per bin
    int b = t >> 1;
    int half = t & 1;
    const float* pr = probes + b * ND;
    float ss = 0.f;
    for (int i = 0; i < ND; i += 4) {
        float4 v = *(const float4*)(pr + i);
        ss += v.x * v.x + v.y * v.y + v.z * v.z + v.w * v.w;
    }
    float scale = 1.f / (sqrtf(ss) + EPSF);
    int f0 = half * 32;
    for (int f = f0; f < f0 + 32; ++f) {
        float p0 = pr[2 * f] * scale;
        float p1 = pr[2 * f + 1] * scale;
        float c = cosf(angles[f]);
        float s = sinf(angles[f]);
        float rx = p0 * c - p1 * s;
        float ry = p0 * s + p1 * c;
        float x = qwr[b * NF + f];
        float sp = fmaxf(x, 0.f) + log1pf(expf(-fabsf(x)));   // softplus, stable
        float ew = -sp;
        float qw = qmw[b * NF + f];
        Ppack[f * NB + b] = make_float4(rx, ry, ew, qw);
        Bfrag[frag_index(2 * f, b)]     = f2bf(rx);
        Bfrag[frag_index(2 * f + 1, b)] = f2bf(ry);
        int kmag = (4 + (f >> 5)) * 32 + ((f >> 2) & 3) * 8 + ((f >> 4) & 1) * 4 + (f & 3);
        Bfrag[frag_index(kmag, b)] = f2bf(kmw[b * NF + f]);
    }
}

// ---------------- k_gemm tile body ------------------------------------------
// cur: this tile's 8 float4 (K row cols kc*32+q*8..+7). nxt: prefetch target.
// Mag frags built in-lane via the k-permutation (no K re-read).
// Epilogue: shuffle-transpose -> float2 stores, 4 full 128B lines per instr.
__device__ __forceinline__ void k_tile(const unsigned short* Blds,
                                       float* __restrict__ out,
                                       const float* __restrict__ Kpre,
                                       const float4 (&cur)[8], float4 (&nxt)[8],
                                       int doPf, size_t orowWave,
                                       int lane, int q, int m,
                                       const float (&bl)[4], const float (&bh)[4]) {
    if (doPf) {
        #pragma unroll
        for (int kc = 0; kc < 4; ++kc) {
            nxt[2 * kc]     = *(const float4*)(Kpre + kc * 32 + q * 8);
            nxt[2 * kc + 1] = *(const float4*)(Kpre + kc * 32 + q * 8 + 4);
        }
    }

    bf16x8 a[6];
    #pragma unroll
    for (int kc = 0; kc < 4; ++kc) {
        union { bf16x8 v; unsigned short s[8]; } u;
        float4 v0 = cur[2 * kc], v1 = cur[2 * kc + 1];
        u.s[0] = f2bf(v0.x); u.s[1] = f2bf(v0.y);
        u.s[2] = f2bf(v0.z); u.s[3] = f2bf(v0.w);
        u.s[4] = f2bf(v1.x); u.s[5] = f2bf(v1.y);
        u.s[6] = f2bf(v1.z); u.s[7] = f2bf(v1.w);
        a[kc] = u.v;
    }
    // pair magnitudes owned by this lane: mg[kc'][jj] = |pair f=kc'*16+q*4+jj|
    float mg[4][4];
    #pragma unroll
    for (int kc = 0; kc < 4; ++kc) {
        float4 v0 = cur[2 * kc], v1 = cur[2 * kc + 1];
        mg[kc][0] = sqrtf(fmaf(v0.x, v0.x, fmaf(v0.y, v0.y, EPSF)));
        mg[kc][1] = sqrtf(fmaf(v0.z, v0.z, fmaf(v0.w, v0.w, EPSF)));
        mg[kc][2] = sqrtf(fmaf(v1.x, v1.x, fmaf(v1.y, v1.y, EPSF)));
        mg[kc][3] = sqrtf(fmaf(v1.z, v1.z, fmaf(v1.w, v1.w, EPSF)));
    }
    #pragma unroll
    for (int h = 0; h < 2; ++h) {
        union { bf16x8 v; unsigned short s[8]; } u;
        #pragma unroll
        for (int j = 0; j < 8; ++j)
            u.s[j] = f2bf(mg[2 * h + (j >> 2)][j & 3]);
        a[4 + h] = u.v;
    }

    f32x4 acc[8];
    #pragma unroll
    for (int i = 0; i < 8; ++i) acc[i] = (f32x4){0.f, 0.f, 0.f, 0.f};
    #pragma unroll
    for (int kc = 0; kc < 6; ++kc) {
        #pragma unroll
        for (int nt = 0; nt < 8; ++nt) {
            bf16x8 bb = *(const bf16x8*)&Blds[((kc * 8 + nt) * 64 + lane) * 8];
            acc[nt] = __builtin_amdgcn_mfma_f32_16x16x32_bf16(a[kc], bb, acc[nt], 0, 0, 0);
        }
    }

    // epilogue: lane stores cols p*32+2m, p*32+2m+1 of row q*4+r
    int src = q * 16 + ((2 * m) & 15);
    #pragma unroll
    for (int p = 0; p < 4; ++p) {
        #pragma unroll
        for (int r = 0; r < 4; ++r) {
            float t0 = __shfl(acc[2 * p][r],     src);
            float u0 = __shfl(acc[2 * p][r],     src + 1);
            float t1 = __shfl(acc[2 * p + 1][r], src);
            float u1 = __shfl(acc[2 * p + 1][r], src + 1);
            float lo = (m < 8) ? t0 : t1;
            float hi = (m < 8) ? u0 : u1;
            size_t off = (orowWave + q * 4 + r) * NB + p * 32 + 2 * m;
            *(float2*)&out[off] = make_float2(lo + bl[p], hi + bh[p]);
        }
    }
}

// ---------------- k_logits: (Nk x 192) @ (192 x 128) bf16 MFMA --------------
// Single read of K (mag frags from dot registers), B LDS-resident (48 KB ->
// 3 blocks/CU), 8 tiles of 64 rows per block, va/vb double-buffer prefetch.
__global__ __launch_bounds__(256, 3)
void k_gemm(const float* __restrict__ Kg,
            const unsigned short* __restrict__ Bfrag_g,
            const float* __restrict__ k_bias,
            float* __restrict__ out) {
    __shared__ unsigned short Blds[6 * 8 * 64 * 8];   // 48 KB
    int t = threadIdx.x;
    int lane = t & 63, w = t >> 6, m = lane & 15, q = lane >> 4;

    size_t rowbase = (size_t)blockIdx.x * 512;
    const float* Kr0 = Kg + (rowbase + (size_t)(w * 16 + m)) * ND;

    float4 va[8], vb[8];
    #pragma unroll
    for (int kc = 0; kc < 4; ++kc) {                  // preload tile 0
        va[2 * kc]     = *(const float4*)(Kr0 + kc * 32 + q * 8);
        va[2 * kc + 1] = *(const float4*)(Kr0 + kc * 32 + q * 8 + 4);
    }

    {   // stage B fragments (48 KB), overlaps with the preload above
        const uint4* src = (const uint4*)Bfrag_g;
        uint4* dst = (uint4*)Blds;
        #pragma unroll
        for (int i = 0; i < 12; ++i) dst[i * 256 + t] = src[i * 256 + t];
    }

    float bl[4], bh[4];
    #pragma unroll
    for (int p = 0; p < 4; ++p) {
        bl[p] = k_bias[p * 32 + 2 * m];
        bh[p] = k_bias[p * 32 + 2 * m + 1];
    }
    __syncthreads();

    #pragma unroll 1
    for (int tt2 = 0; tt2 < 4; ++tt2) {
        size_t r0 = rowbase + (size_t)(2 * tt2) * 64;
        const float* pf1 = Kg + (r0 + 64 + (size_t)(w * 16 + m)) * ND;
        k_tile(Blds, out, pf1, va, vb, 1, r0 + w * 16, lane, q, m, bl, bh);
        const float* pf2 = Kg + (r0 + 128 + (size_t)(w * 16 + m)) * ND;
        k_tile(Blds, out, pf2, vb, va, (tt2 < 3) ? 1 : 0, r0 + 64 + w * 16,
               lane, q, m, bl, bh);
    }
}

// ---------------- q_logits: distance scoring, register-tiled 4 bins x 2 rows
__global__ __launch_bounds__(256, 2)
void q_kernel(const float* __restrict__ Qg,
              const float4* __restrict__ Ppack,
              const float* __restrict__ q_bias,
              float* __restrict__ outq) {
    __shared__ float4 Plds[64 * 32];      // 32 KB
    __shared__ float  Qlds[64 * 130];     // 33.3 KB (qx,qy pairs, padded stride)
    int t = threadIdx.x;
    int bg = blockIdx.x & 3;              // bin group (32 bins)
    int rb = blockIdx.x >> 2;             // row block (64 rows)

    #pragma unroll
    for (int i = 0; i < 8; ++i) {
        int idx = i * 256 + t;            // 0..2047
        int f = idx >> 5, bl = idx & 31;
        Plds[idx] = Ppack[f * NB + bg * 32 + bl];
    }
    #pragma unroll
    for (int i = 0; i < 8; ++i) {
        int r = i * 8 + (t >> 5);         // 0..63
        int c = t & 31;
        float4 v = *(const float4*)(Qg + (size_t)(rb * 64 + r) * ND + c * 4);
        float ss = v.x * v.x + v.y * v.y + v.z * v.z + v.w * v.w;
        #pragma unroll
        for (int msk = 1; msk < 32; msk <<= 1) ss += __shfl_xor(ss, msk);
        float inv = 1.f / (sqrtf(ss) + EPSF);
        *(float2*)&Qlds[r * 130 + c * 4]     = make_float2(v.x * inv, v.y * inv);
        *(float2*)&Qlds[r * 130 + c * 4 + 2] = make_float2(v.z * inv, v.w * inv);
    }
    __syncthreads();

    int lane = t & 63, w = t >> 6;
    int rp = lane >> 3, bo = lane & 7;
    int r0 = w * 16 + rp * 2, r1 = r0 + 1;

    float acc[4][2] = {};
    #pragma unroll 8
    for (int f = 0; f < 64; ++f) {
        float2 q0 = *(const float2*)&Qlds[r0 * 130 + 2 * f];
        float2 q1 = *(const float2*)&Qlds[r1 * 130 + 2 * f];
        float qm0 = sqrtf(fmaf(q0.x, q0.x, fmaf(q0.y, q0.y, EPSF)));
        float qm1 = sqrtf(fmaf(q1.x, q1.x, fmaf(q1.y, q1.y, EPSF)));
        #pragma unroll
        for (int k = 0; k < 4; ++k) {
            float4 P = Plds[f * 32 + k * 8 + bo];
            float dx0 = P.x - q0.x, dy0 = P.y - q0.y;
            float d0 = sqrtf(fmaf(dx0, dx0, fmaf(dy0, dy0, EPSF)));
            acc[k][0] = fmaf(P.z, d0, acc[k][0]);
            acc[k][0] = fmaf(P.w, qm0, acc[k][0]);
            float dx1 = P.x - q1.x, dy1 = P.y - q1.y;
            float d1 = sqrtf(fmaf(dx1, dx1, fmaf(dy1, dy1, EPSF)));
            acc[k][1] = fmaf(P.z, d1, acc[k][1]);
            acc[k][1] = fmaf(P.w, qm1, acc[k][1]);
        }
    }
    #pragma unroll
    for (int k = 0; k < 4; ++k) {
        int col = bg * 32 + k * 8 + bo;
        float bias = q_bias[col];
        outq[(size_t)(rb * 64 + r0) * NB + col] = acc[k][0] + bias;
        outq[(size_t)(rb * 64 + r1) * NB + col] = acc[k][1] + bias;
    }
}

extern "C" void kernel_launch(void* const* d_in, const int* in_sizes, int n_in,
                              void* d_out, int out_size, void* d_ws, size_t ws_size,
                              hipStream_t stream) {
    const float* Q      = (const float*)d_in[0];
    const float* K      = (const float*)d_in[1];
    const float* angles = (const float*)d_in[2];
    const float* probes = (const float*)d_in[3];
    const float* kmw    = (const float*)d_in[4];
    const float* kb     = (const float*)d_in[5];
    const float* qwr    = (const float*)d_in[6];
    const float* qmw    = (const float*)d_in[7];
    const float* qb     = (const float*)d_in[8];
    float* out = (float*)d_out;

    unsigned short* Bfrag = (unsigned short*)d_ws;                 // 49152 B
    float4* Ppack = (float4*)((char*)d_ws + 65536);                // 131072 B

    prep_kernel<<<1, 256, 0, stream>>>(angles, probes, kmw, qwr, qmw, Bfrag, Ppack);
    k_gemm<<<NK / 512, 256, 0, stream>>>(K, Bfrag, kb, out);
    q_kernel<<<(NQ / 64) * 4, 256, 0, stream>>>(Q, Ppack, qb, out + (size_t)NK * NB);
}

// Round 5
// 608.981 us; speedup vs baseline: 1.4027x; 1.4027x over previous
//
#include <hip/hip_runtime.h>
#include <hip/hip_bf16.h>
#include <math.h>

#define NQ 8192
#define NK 524288
#define NB 128
#define NF 64
#define ND 128
#define EPSF 1e-8f

using bf16x8 = __attribute__((ext_vector_type(8))) short;
using f32x4  = __attribute__((ext_vector_type(4))) float;

__device__ __forceinline__ unsigned short f2bf(float x) {
    union { float f; unsigned int u; } v; v.f = x;
    unsigned int u = v.u;
    return (unsigned short)((u + 0x7FFFu + ((u >> 16) & 1u)) >> 16);
}

// Bfrag layout: [kc(6)][nt(8)][lane(64)][j(8)] bf16, B[k][n] with
// n = nt*16 + (lane&15), k = kc*32 + (lane>>4)*8 + j ; value = content(k) of col n
__device__ __forceinline__ int frag_index(int k, int b) {
    int kc = k >> 5, kl = k & 31, quad = kl >> 3, j = kl & 7;
    int nt = b >> 4, ln = (quad << 4) | (b & 15);
    return ((kc * 8 + nt) * 64 + ln) * 8 + j;
}

// ---------------- prep: rotated probes, softplus weights, frag scatter ------
// Mag k-slots are PERMUTED so k_gemm lanes build mag frags from their own
// dot-load registers: slot (kc=4+h, quad, j) holds mag index
// f = (2h + (j>>2))*16 + quad*4 + (j&3). Inverse used here:
// k(f) = (4 + (f>>5))*32 + ((f>>2)&3)*8 + ((f>>4)&1)*4 + (f&3).
__global__ void prep_kernel(const float* __restrict__ angles,
                            const float* __restrict__ probes,
                            const float* __restrict__ kmw,
                            const float* __restrict__ qwr,
                            const float* __restrict__ qmw,
                            unsigned short* __restrict__ Bfrag,
                            float4* __restrict__ Ppack) {
    int t = threadIdx.x;          // 256 threads: 2 per bin
    int b = t >> 1;
    int half = t & 1;
    const float* pr = probes + b * ND;
    float ss = 0.f;
    for (int i = 0; i < ND; i += 4) {
        float4 v = *(const float4*)(pr + i);
        ss += v.x * v.x + v.y * v.y + v.z * v.z + v.w * v.w;
    }
    float scale = 1.f / (sqrtf(ss) + EPSF);
    int f0 = half * 32;
    for (int f = f0; f < f0 + 32; ++f) {
        float p0 = pr[2 * f] * scale;
        float p1 = pr[2 * f + 1] * scale;
        float c = cosf(angles[f]);
        float s = sinf(angles[f]);
        float rx = p0 * c - p1 * s;
        float ry = p0 * s + p1 * c;
        float x = qwr[b * NF + f];
        float sp = fmaxf(x, 0.f) + log1pf(expf(-fabsf(x)));   // softplus, stable
        float ew = -sp;
        float qw = qmw[b * NF + f];
        Ppack[f * NB + b] = make_float4(rx, ry, ew, qw);
        Bfrag[frag_index(2 * f, b)]     = f2bf(rx);
        Bfrag[frag_index(2 * f + 1, b)] = f2bf(ry);
        int kmag = (4 + (f >> 5)) * 32 + ((f >> 2) & 3) * 8 + ((f >> 4) & 1) * 4 + (f & 3);
        Bfrag[frag_index(kmag, b)] = f2bf(kmw[b * NF + f]);
    }
}

// ---------------- k_logits: (Nk x 192) @ (192 x 128) bf16 MFMA --------------
// Single K read (mag frags from dot registers via k-permutation), B LDS-
// resident (48 KB). Pipeline per tile: convert va->a (va dies) -> issue next
// tile's loads into va -> MFMA + epilogue hide the load latency.
// __launch_bounds__(256,2): 256-VGPR budget so nothing spills (round-4 lesson:
// (256,3) squeezed to 84 VGPR and spilled the pipeline regs -> +500MB HBM).
__global__ __launch_bounds__(256, 2)
void k_gemm(const float* __restrict__ Kg,
            const unsigned short* __restrict__ Bfrag_g,
            const float* __restrict__ k_bias,
            float* __restrict__ out) {
    __shared__ unsigned short Blds[6 * 8 * 64 * 8];   // 48 KB
    int t = threadIdx.x;
    int lane = t & 63, w = t >> 6, m = lane & 15, q = lane >> 4;

    size_t rowbase = (size_t)blockIdx.x * 512;
    const float* Kr0 = Kg + (rowbase + (size_t)(w * 16 + m)) * ND;

    float4 va[8];
    #pragma unroll
    for (int kc = 0; kc < 4; ++kc) {                  // preload tile 0
        va[2 * kc]     = *(const float4*)(Kr0 + kc * 32 + q * 8);
        va[2 * kc + 1] = *(const float4*)(Kr0 + kc * 32 + q * 8 + 4);
    }

    {   // stage B fragments (48 KB, L2-hot); overlaps the preload above
        const uint4* src = (const uint4*)Bfrag_g;
        uint4* dst = (uint4*)Blds;
        #pragma unroll
        for (int i = 0; i < 12; ++i) dst[i * 256 + t] = src[i * 256 + t];
    }

    float bl[4], bh[4];
    #pragma unroll
    for (int p = 0; p < 4; ++p) {
        bl[p] = k_bias[p * 32 + 2 * m];
        bh[p] = k_bias[p * 32 + 2 * m + 1];
    }
    __syncthreads();

    #pragma unroll 1
    for (int tt = 0; tt < 8; ++tt) {
        // ---- convert current tile: va -> a[6] (va dead afterwards) ----
        bf16x8 a[6];
        #pragma unroll
        for (int kc = 0; kc < 4; ++kc) {
            union { bf16x8 v; unsigned short s[8]; } u;
            float4 v0 = va[2 * kc], v1 = va[2 * kc + 1];
            u.s[0] = f2bf(v0.x); u.s[1] = f2bf(v0.y);
            u.s[2] = f2bf(v0.z); u.s[3] = f2bf(v0.w);
            u.s[4] = f2bf(v1.x); u.s[5] = f2bf(v1.y);
            u.s[6] = f2bf(v1.z); u.s[7] = f2bf(v1.w);
            a[kc] = u.v;
        }
        {   // pair magnitudes owned by this lane: mg[kc'][jj] = |pair kc'*16+q*4+jj|
            float mg[4][4];
            #pragma unroll
            for (int kc = 0; kc < 4; ++kc) {
                float4 v0 = va[2 * kc], v1 = va[2 * kc + 1];
                mg[kc][0] = sqrtf(fmaf(v0.x, v0.x, fmaf(v0.y, v0.y, EPSF)));
                mg[kc][1] = sqrtf(fmaf(v0.z, v0.z, fmaf(v0.w, v0.w, EPSF)));
                mg[kc][2] = sqrtf(fmaf(v1.x, v1.x, fmaf(v1.y, v1.y, EPSF)));
                mg[kc][3] = sqrtf(fmaf(v1.z, v1.z, fmaf(v1.w, v1.w, EPSF)));
            }
            #pragma unroll
            for (int h = 0; h < 2; ++h) {
                union { bf16x8 v; unsigned short s[8]; } u;
                #pragma unroll
                for (int j = 0; j < 8; ++j)
                    u.s[j] = f2bf(mg[2 * h + (j >> 2)][j & 3]);
                a[4 + h] = u.v;
            }
        }

        // ---- issue next tile's loads into the now-dead va ----
        if (tt < 7) {
            const float* Kn = Kg + (rowbase + (size_t)((tt + 1) * 64 + w * 16 + m)) * ND;
            #pragma unroll
            for (int kc = 0; kc < 4; ++kc) {
                va[2 * kc]     = *(const float4*)(Kn + kc * 32 + q * 8);
                va[2 * kc + 1] = *(const float4*)(Kn + kc * 32 + q * 8 + 4);
            }
        }

        // ---- MFMA ----
        f32x4 acc[8];
        #pragma unroll
        for (int i = 0; i < 8; ++i) acc[i] = (f32x4){0.f, 0.f, 0.f, 0.f};
        #pragma unroll
        for (int kc = 0; kc < 6; ++kc) {
            #pragma unroll
            for (int nt = 0; nt < 8; ++nt) {
                bf16x8 bb = *(const bf16x8*)&Blds[((kc * 8 + nt) * 64 + lane) * 8];
                acc[nt] = __builtin_amdgcn_mfma_f32_16x16x32_bf16(a[kc], bb, acc[nt], 0, 0, 0);
            }
        }

        // ---- epilogue: shuffle-transpose -> float2 stores (full 128B lines)
        // lane stores cols p*32+2m, p*32+2m+1 of row q*4+r
        size_t orowWave = rowbase + (size_t)(tt * 64 + w * 16);
        int src = q * 16 + ((2 * m) & 15);
        #pragma unroll
        for (int p = 0; p < 4; ++p) {
            #pragma unroll
            for (int r = 0; r < 4; ++r) {
                float t0 = __shfl(acc[2 * p][r],     src);
                float u0 = __shfl(acc[2 * p][r],     src + 1);
                float t1 = __shfl(acc[2 * p + 1][r], src);
                float u1 = __shfl(acc[2 * p + 1][r], src + 1);
                float lo = (m < 8) ? t0 : t1;
                float hi = (m < 8) ? u0 : u1;
                size_t off = (orowWave + q * 4 + r) * NB + p * 32 + 2 * m;
                *(float2*)&out[off] = make_float2(lo + bl[p], hi + bh[p]);
            }
        }
    }
}

// ---------------- q_logits: distance scoring, register-tiled 4 bins x 2 rows
__global__ __launch_bounds__(256, 2)
void q_kernel(const float* __restrict__ Qg,
              const float4* __restrict__ Ppack,
              const float* __restrict__ q_bias,
              float* __restrict__ outq) {
    __shared__ float4 Plds[64 * 32];      // 32 KB
    __shared__ float  Qlds[64 * 130];     // 33.3 KB (qx,qy pairs, padded stride)
    int t = threadIdx.x;
    int bg = blockIdx.x & 3;              // bin group (32 bins)
    int rb = blockIdx.x >> 2;             // row block (64 rows)

    #pragma unroll
    for (int i = 0; i < 8; ++i) {
        int idx = i * 256 + t;            // 0..2047
        int f = idx >> 5, bl = idx & 31;
        Plds[idx] = Ppack[f * NB + bg * 32 + bl];
    }
    #pragma unroll
    for (int i = 0; i < 8; ++i) {
        int r = i * 8 + (t >> 5);         // 0..63
        int c = t & 31;
        float4 v = *(const float4*)(Qg + (size_t)(rb * 64 + r) * ND + c * 4);
        float ss = v.x * v.x + v.y * v.y + v.z * v.z + v.w * v.w;
        #pragma unroll
        for (int msk = 1; msk < 32; msk <<= 1) ss += __shfl_xor(ss, msk);
        float inv = 1.f / (sqrtf(ss) + EPSF);
        *(float2*)&Qlds[r * 130 + c * 4]     = make_float2(v.x * inv, v.y * inv);
        *(float2*)&Qlds[r * 130 + c * 4 + 2] = make_float2(v.z * inv, v.w * inv);
    }
    __syncthreads();

    int lane = t & 63, w = t >> 6;
    int rp = lane >> 3, bo = lane & 7;
    int r0 = w * 16 + rp * 2, r1 = r0 + 1;

    float acc[4][2] = {};
    #pragma unroll 8
    for (int f = 0; f < 64; ++f) {
        float2 q0 = *(const float2*)&Qlds[r0 * 130 + 2 * f];
        float2 q1 = *(const float2*)&Qlds[r1 * 130 + 2 * f];
        float qm0 = sqrtf(fmaf(q0.x, q0.x, fmaf(q0.y, q0.y, EPSF)));
        float qm1 = sqrtf(fmaf(q1.x, q1.x, fmaf(q1.y, q1.y, EPSF)));
        #pragma unroll
        for (int k = 0; k < 4; ++k) {
            float4 P = Plds[f * 32 + k * 8 + bo];
            float dx0 = P.x - q0.x, dy0 = P.y - q0.y;
            float d0 = sqrtf(fmaf(dx0, dx0, fmaf(dy0, dy0, EPSF)));
            acc[k][0] = fmaf(P.z, d0, acc[k][0]);
            acc[k][0] = fmaf(P.w, qm0, acc[k][0]);
            float dx1 = P.x - q1.x, dy1 = P.y - q1.y;
            float d1 = sqrtf(fmaf(dx1, dx1, fmaf(dy1, dy1, EPSF)));
            acc[k][1] = fmaf(P.z, d1, acc[k][1]);
            acc[k][1] = fmaf(P.w, qm1, acc[k][1]);
        }
    }
    #pragma unroll
    for (int k = 0; k < 4; ++k) {
        int col = bg * 32 + k * 8 + bo;
        float bias = q_bias[col];
        outq[(size_t)(rb * 64 + r0) * NB + col] = acc[k][0] + bias;
        outq[(size_t)(rb * 64 + r1) * NB + col] = acc[k][1] + bias;
    }
}

extern "C" void kernel_launch(void* const* d_in, const int* in_sizes, int n_in,
                              void* d_out, int out_size, void* d_ws, size_t ws_size,
                              hipStream_t stream) {
    const float* Q      = (const float*)d_in[0];
    const float* K      = (const float*)d_in[1];
    const float* angles = (const float*)d_in[2];
    const float* probes = (const float*)d_in[3];
    const float* kmw    = (const float*)d_in[4];
    const float* kb     = (const float*)d_in[5];
    const float* qwr    = (const float*)d_in[6];
    const float* qmw    = (const float*)d_in[7];
    const float* qb     = (const float*)d_in[8];
    float* out = (float*)d_out;

    unsigned short* Bfrag = (unsigned short*)d_ws;                 // 49152 B
    float4* Ppack = (float4*)((char*)d_ws + 65536);                // 131072 B

    prep_kernel<<<1, 256, 0, stream>>>(angles, probes, kmw, qwr, qmw, Bfrag, Ppack);
    k_gemm<<<NK / 512, 256, 0, stream>>>(K, Bfrag, kb, out);
    q_kernel<<<(NQ / 64) * 4, 256, 0, stream>>>(Q, Ppack, qb, out + (size_t)NK * NB);
}